// Round 2
// baseline (545.971 us; speedup 1.0000x reference)
//
#include <hip/hip_runtime.h>

typedef unsigned short u16;
typedef short v8s __attribute__((ext_vector_type(8)));
typedef float v4f __attribute__((ext_vector_type(4)));

// ---- problem constants ----
#define KDIM 768
#define M_TEXT 1536            // 32*48
#define N_VOCAB 30522
#define N_VOCAB_PAD 30592      // 239*128 (B buffer rows; zero-padded 30522..30591)
#define M_HC 1056              // 32*33
#define M_HC_PAD 1152          // 9*128
#define N_IOU 2304             // 3*768
#define OUT_IOU_OFF 46881792
#define OUT_MASK_OFF 46983168

__device__ __forceinline__ u16 f2bf(float f) {
  unsigned u = __float_as_uint(f);
  u += 0x7fffu + ((u >> 16) & 1u);   // RNE
  return (u16)(u >> 16);
}

// ---------------- prep: convert activations to bf16 (hc padded to 1152 rows) -------------
__global__ __launch_bounds__(256) void prep_cvt(const float* __restrict__ xt_in,
                                                const float* __restrict__ hc_in,
                                                u16* __restrict__ xt,
                                                u16* __restrict__ hcb) {
  const int NXT = M_TEXT * KDIM / 4;      // 294912 float4s
  int i = blockIdx.x * 256 + threadIdx.x; // grid sized exactly (294912+221184)/256
  if (i < NXT) {
    float4 v = ((const float4*)xt_in)[i];
    ushort4 o; o.x = f2bf(v.x); o.y = f2bf(v.y); o.z = f2bf(v.z); o.w = f2bf(v.w);
    ((ushort4*)xt)[i] = o;
  } else {
    int j = i - NXT;                      // < 1152*192
    int row = j / 192;
    float4 v = make_float4(0.f, 0.f, 0.f, 0.f);
    if (row < M_HC) v = ((const float4*)hc_in)[j];
    ushort4 o; o.x = f2bf(v.x); o.y = f2bf(v.y); o.z = f2bf(v.z); o.w = f2bf(v.w);
    ((ushort4*)hcb)[j] = o;
  }
}

// ---------------- transpose + convert: in fp32 (768 x C) -> out bf16 (Cpad x 768) --------
__global__ __launch_bounds__(256) void transpose_cvt(const float* __restrict__ in,
                                                     u16* __restrict__ out,
                                                     int C, long inBatch, long outBatch) {
  __shared__ float tile[64][65];
  const float* ip = in + (long)blockIdx.z * inBatch;
  u16* op = out + (long)blockIdx.z * outBatch;
  int r0 = blockIdx.x * 64, c0 = blockIdx.y * 64;
  int tx = threadIdx.x & 63, tg = threadIdx.x >> 6;
#pragma unroll
  for (int i = 0; i < 16; ++i) {
    int r = tg + i * 4;
    int gc = c0 + tx;
    tile[r][tx] = (gc < C) ? ip[(long)(r0 + r) * C + gc] : 0.f;
  }
  __syncthreads();
#pragma unroll
  for (int i = 0; i < 16; ++i) {
    int cc = tg + i * 4;
    op[(long)(c0 + cc) * KDIM + r0 + tx] = f2bf(tile[tx][cc]);
  }
}

// ---------------- mask map ----------------
__global__ void mask_kernel(float* __restrict__ out) {
  int idx = blockIdx.x * 256 + threadIdx.x;
  if (idx >= 1056) return;
  int i = idx / 33, j = idx % 33;
  float v = 0.f;
  int hi = min(i + 17, 33);
  if (j >= i + 1 && j < hi) v = 1.f;
  if ((i & 1) == 0 && i < 16 && j >= 18 + i && ((j - (18 + i)) & 1) == 0) v = 1.f;
  out[OUT_MASK_OFF + idx] = v;
}

// ---------------- m97-style 128^2 GEMM (kept for the two small GEMMs) ----------------
// MODE 1: bfout = bf16(relu(acc + bias[c])), ldc
// MODE 2: fout = acc (no bias, no guard), ldc
template <int MODE>
__global__ __launch_bounds__(256)
void gemm_bt(const u16* __restrict__ A, const u16* __restrict__ BT,
             float* __restrict__ fout, u16* __restrict__ bfout,
             const float* __restrict__ bias, int ldc, int nmax) {
  __shared__ u16 sA[128 * 32];
  __shared__ u16 sB[128 * 32];
  const int tid = threadIdx.x;
  const int wid = tid >> 6;
  const int lane = tid & 63;
  const int lrow = lane & 15;
  const int quad = lane >> 4;
  const int wm = (wid & 1) * 64;
  const int wn = (wid >> 1) * 64;
  const int m0 = blockIdx.y * 128;
  const int n0 = blockIdx.x * 128;

  const int srow = wid * 32 + (lane >> 2);
  const int scol = (lane & 3) * 8;
  const u16* gA = A + (long)(m0 + srow) * KDIM + scol;
  const u16* gB = BT + (long)(n0 + srow) * KDIM + scol;
  u16* lA = &sA[(wid * 32) * 32];
  u16* lB = &sB[(wid * 32) * 32];

  v4f acc[4][4];
#pragma unroll
  for (int i = 0; i < 4; ++i)
#pragma unroll
    for (int j = 0; j < 4; ++j) acc[i][j] = (v4f){0.f, 0.f, 0.f, 0.f};

  const v8s* pA = (const v8s*)sA;
  const v8s* pB = (const v8s*)sB;
  const int ia0 = (wm + lrow) * 4 + quad;
  const int ib0 = (wn + lrow) * 4 + quad;

  for (int kt = 0; kt < KDIM / 32; ++kt) {
    const u16* ga = gA + kt * 32;
    const u16* gb = gB + kt * 32;
    __builtin_amdgcn_global_load_lds((const __attribute__((address_space(1))) void*)ga,
                                     (__attribute__((address_space(3))) void*)lA, 16, 0, 0);
    __builtin_amdgcn_global_load_lds((const __attribute__((address_space(1))) void*)(ga + 16 * KDIM),
                                     (__attribute__((address_space(3))) void*)(lA + 16 * 32), 16, 0, 0);
    __builtin_amdgcn_global_load_lds((const __attribute__((address_space(1))) void*)gb,
                                     (__attribute__((address_space(3))) void*)lB, 16, 0, 0);
    __builtin_amdgcn_global_load_lds((const __attribute__((address_space(1))) void*)(gb + 16 * KDIM),
                                     (__attribute__((address_space(3))) void*)(lB + 16 * 32), 16, 0, 0);
    __syncthreads();

    v8s af[4], bfr[4];
#pragma unroll
    for (int mt = 0; mt < 4; ++mt) af[mt] = pA[ia0 + mt * 64];
#pragma unroll
    for (int nt = 0; nt < 4; ++nt) bfr[nt] = pB[ib0 + nt * 64];
#pragma unroll
    for (int mt = 0; mt < 4; ++mt)
#pragma unroll
      for (int nt = 0; nt < 4; ++nt)
        acc[mt][nt] = __builtin_amdgcn_mfma_f32_16x16x32_bf16(af[mt], bfr[nt], acc[mt][nt], 0, 0, 0);
    __syncthreads();
  }

#pragma unroll
  for (int nt = 0; nt < 4; ++nt) {
    int c = n0 + wn + nt * 16 + lrow;
    float bv = 0.f;
    if (MODE == 1) bv = bias[c];
#pragma unroll
    for (int mt = 0; mt < 4; ++mt) {
#pragma unroll
      for (int r = 0; r < 4; ++r) {
        int row = m0 + wm + mt * 16 + quad * 4 + r;
        float v = acc[mt][nt][r] + bv;
        if (MODE == 1) {
          bfout[(long)row * ldc + c] = f2bf(fmaxf(v, 0.f));
        } else {
          fout[(long)row * ldc + c] = v;
        }
      }
    }
  }
}

// ================= big vocab GEMM: 256x256 tile, 8 waves, BK=64, 8-phase =================
// C[1536, 30522(+pad)] = htext[1536,768] * w_t2T[30592,768]^T + bias
// Loop: unchanged from round 1 (verified). Epilogue: LDS-staged coalesced row stores.
#define DSREAD_B(sB) do {                                                  \
    const u16* _b = (sB) + bBase;                                          \
    _Pragma("unroll")                                                      \
    for (int _nf = 0; _nf < 4; ++_nf) {                                    \
      bfr[_nf][0] = *(const v8s*)(_b + _nf * 1024 + c0);                   \
      bfr[_nf][1] = *(const v8s*)(_b + _nf * 1024 + c1);                   \
    } } while (0)

#define DSREAD_A(sA, q) do {                                               \
    const u16* _a = (sA) + aBase + (q) * 2048;                             \
    af[0][0] = *(const v8s*)(_a + c0);                                     \
    af[0][1] = *(const v8s*)(_a + c1);                                     \
    af[1][0] = *(const v8s*)(_a + 1024 + c0);                              \
    af[1][1] = *(const v8s*)(_a + 1024 + c1);                              \
  } while (0)

#define MFMA_Q(q) do {                                                     \
    _Pragma("unroll")                                                      \
    for (int _m = 0; _m < 2; ++_m)                                         \
      _Pragma("unroll")                                                    \
      for (int _nf = 0; _nf < 4; ++_nf) {                                  \
        acc[2*(q)+_m][_nf] = __builtin_amdgcn_mfma_f32_16x16x32_bf16(      \
            af[_m][0], bfr[_nf][0], acc[2*(q)+_m][_nf], 0, 0, 0);          \
        acc[2*(q)+_m][_nf] = __builtin_amdgcn_mfma_f32_16x16x32_bf16(      \
            af[_m][1], bfr[_nf][1], acc[2*(q)+_m][_nf], 0, 0, 0);          \
      } } while (0)

#define BAR_SB() do { __builtin_amdgcn_s_barrier();                        \
                      __builtin_amdgcn_sched_barrier(0); } while (0)
#define LGKM0() do { asm volatile("s_waitcnt lgkmcnt(0)" ::: "memory");    \
                     __builtin_amdgcn_sched_barrier(0); } while (0)

__global__ __launch_bounds__(512, 2)
void gemm_big(const u16* __restrict__ A, const u16* __restrict__ BT,
              float* __restrict__ out, const float* __restrict__ bias) {
  __shared__ u16 sbuf[2][2][256 * 64];   // [buf][0=A,1=B], 128 KiB total

  // T1: XCD-chunked, M-fastest remap. 720 blocks, 8 XCDs, chunk = 90.
  const int id = blockIdx.x;
  const int swz = (id & 7) * 90 + (id >> 3);
  const int mt = swz % 6;
  const int nt = swz / 6;
  const int m0 = mt * 256, n0 = nt * 256;

  const int tid = threadIdx.x;
  const int wid = tid >> 6;
  const int lane = tid & 63;
  const int l3 = lane >> 3;            // 0..7 (row within 8-row chunk)
  const int l7 = lane & 7;
  const int lrow = lane & 15;
  const int quad = lane >> 4;
  const int wr = wid >> 2;             // 0..1  -> wave's 128-row half of M
  const int wc = wid & 3;              // 0..3  -> wave's 64-col slice of N

  // staging: pre-swizzled global source, linear LDS dest (rule #21)
  const int xc = (l7 ^ l3) * 8;        // swizzled K column (elements)
  const u16* Ag = A  + (long)(m0 + wid * 16 + l3) * KDIM + xc;
  const u16* Bg = BT + (long)(n0 + wid * 16 + l3) * KDIM + xc;

  u16* const sA0 = &sbuf[0][0][0];
  u16* const sB0 = &sbuf[0][1][0];
  u16* const sA1 = &sbuf[1][0][0];
  u16* const sB1 = &sbuf[1][1][0];

  auto stageA = [&](u16* sdst, int kt, int h) {
#pragma unroll
    for (int j = 0; j < 2; ++j)
      __builtin_amdgcn_global_load_lds(
          (const __attribute__((address_space(1))) void*)(Ag + (long)kt * 64 +
                                                          (long)((h * 128 + j * 8) * KDIM)),
          (__attribute__((address_space(3))) void*)(sdst + (h * 128 + wid * 16 + j * 8) * 64),
          16, 0, 0);
  };
  auto stageB = [&](u16* sdst, int kt, int h) {
    // last N-tile: rows >= 30592 don't exist; clamp source (cols >= 30522 never stored)
    const int hh = (n0 + h * 128 >= N_VOCAB_PAD) ? 0 : h;
#pragma unroll
    for (int j = 0; j < 2; ++j)
      __builtin_amdgcn_global_load_lds(
          (const __attribute__((address_space(1))) void*)(Bg + (long)kt * 64 +
                                                          (long)((hh * 128 + j * 8) * KDIM)),
          (__attribute__((address_space(3))) void*)(sdst + (h * 128 + wid * 16 + j * 8) * 64),
          16, 0, 0);
  };

  // ds_read fragment addressing (swizzled): elem = row*64 + ((ks*32+quad*8) ^ (row&7)*8)
  const int aBase = (wr * 128 + lrow) * 64;
  const int bBase = (wc * 64 + lrow) * 64;
  const int xls = (lrow & 7) * 8;
  const int c0 = (quad * 8) ^ xls;
  const int c1 = c0 ^ 32;

  v4f acc[8][4];
#pragma unroll
  for (int i = 0; i < 8; ++i)
#pragma unroll
    for (int j = 0; j < 4; ++j) acc[i][j] = (v4f){0.f, 0.f, 0.f, 0.f};

  v8s bfr[4][2];
  v8s af[2][2];

  // ---- prologue: b0 (k=0) fully + b1.B (k=1); b1.A(k=1) staged in iter0 ph1/2 ----
  stageA(sA0, 0, 0); stageA(sA0, 0, 1);
  stageB(sB0, 0, 0); stageB(sB0, 0, 1);
  stageB(sB1, 1, 0); stageB(sB1, 1, 1);
  asm volatile("s_waitcnt vmcnt(4)" ::: "memory");   // b0's 8 loads done, b1.B in flight
  __builtin_amdgcn_sched_barrier(0);
  BAR_SB();

#pragma unroll 1
  for (int it = 0; it < 6; ++it) {
    const int kA1 = 2 * it + 1;        // b1.A target (always valid)
    const int kB0 = 2 * it + 2;        // b0 target
    const int kB1 = 2 * it + 3;        // b1.B target
    const bool more = (it < 5);

    // ---- PH1 (buf0, quad0): read all B-frags + A q0; stage b1.A h0 ----
    DSREAD_B(sB0);
    DSREAD_A(sA0, 0);
    stageA(sA1, kA1, 0);
    __builtin_amdgcn_s_barrier();
    LGKM0();
    __builtin_amdgcn_s_setprio(1); MFMA_Q(0); __builtin_amdgcn_s_setprio(0);
    BAR_SB();

    // ---- PH2 ----
    DSREAD_A(sA0, 1);
    stageA(sA1, kA1, 1);
    __builtin_amdgcn_s_barrier();
    LGKM0();
    __builtin_amdgcn_s_setprio(1); MFMA_Q(1); __builtin_amdgcn_s_setprio(0);
    BAR_SB();

    // ---- PH3 ----
    DSREAD_A(sA0, 2);
    if (more) stageB(sB0, kB0, 0);
    __builtin_amdgcn_s_barrier();
    LGKM0();
    __builtin_amdgcn_s_setprio(1); MFMA_Q(2); __builtin_amdgcn_s_setprio(0);
    BAR_SB();

    // ---- PH4: counted wait (b1.B[prev] + b1.A h0/h1 must be resident for PH5) ----
    DSREAD_A(sA0, 3);
    if (more) stageB(sB0, kB0, 1);
    __builtin_amdgcn_s_barrier();
    LGKM0();
    __builtin_amdgcn_s_setprio(1); MFMA_Q(3); __builtin_amdgcn_s_setprio(0);
    if (more) { asm volatile("s_waitcnt vmcnt(4)" ::: "memory"); }
    else      { asm volatile("s_waitcnt vmcnt(0)" ::: "memory"); }
    __builtin_amdgcn_sched_barrier(0);
    BAR_SB();

    // ---- PH5 (buf1, quad0): read all B-frags + A q0; stage b0.A h0 ----
    DSREAD_B(sB1);
    DSREAD_A(sA1, 0);
    if (more) stageA(sA0, kB0, 0);
    __builtin_amdgcn_s_barrier();
    LGKM0();
    __builtin_amdgcn_s_setprio(1); MFMA_Q(0); __builtin_amdgcn_s_setprio(0);
    BAR_SB();

    // ---- PH6 ----
    DSREAD_A(sA1, 1);
    if (more) stageA(sA0, kB0, 1);
    __builtin_amdgcn_s_barrier();
    LGKM0();
    __builtin_amdgcn_s_setprio(1); MFMA_Q(1); __builtin_amdgcn_s_setprio(0);
    BAR_SB();

    // ---- PH7 ----
    DSREAD_A(sA1, 2);
    if (more) stageB(sB1, kB1, 0);
    __builtin_amdgcn_s_barrier();
    LGKM0();
    __builtin_amdgcn_s_setprio(1); MFMA_Q(2); __builtin_amdgcn_s_setprio(0);
    BAR_SB();

    // ---- PH8: counted wait (b0.B + b0.A must be resident for next PH1) ----
    DSREAD_A(sA1, 3);
    if (more) stageB(sB1, kB1, 1);
    __builtin_amdgcn_s_barrier();
    LGKM0();
    __builtin_amdgcn_s_setprio(1); MFMA_Q(3); __builtin_amdgcn_s_setprio(0);
    if (more) { asm volatile("s_waitcnt vmcnt(4)" ::: "memory");
                __builtin_amdgcn_sched_barrier(0); }
    BAR_SB();
  }

  // ---- epilogue: LDS-staged coalesced row stores ----
  // Chunk ch covers tile rows [ch*64, ch*64+64). Owning waves (wr == ch>>1)
  // deposit acc(+bias) into sc[64][260] (f32, 2-way bank aliasing = free),
  // then all 8 waves stream 8 rows each as two contiguous 512B float2 spans.
  // Row base byte offset = row*122088 (== 0 mod 8), so float2 stores are aligned.
  float* sc = (float*)&sbuf[0][0][0];    // 64*260*4 = 66,560 B < 128 KiB
  float bv[4];
#pragma unroll
  for (int nf = 0; nf < 4; ++nf) {
    int col = n0 + wc * 64 + nf * 16 + lrow;
    bv[nf] = (col < N_VOCAB) ? bias[col] : 0.f;
  }
#pragma unroll 1
  for (int ch = 0; ch < 4; ++ch) {
    __syncthreads();
    if (wr == (ch >> 1)) {
      const int mh = (ch & 1) * 4;
#pragma unroll
      for (int mfL = 0; mfL < 4; ++mfL)
#pragma unroll
        for (int nf = 0; nf < 4; ++nf)
#pragma unroll
          for (int rr = 0; rr < 4; ++rr)
            sc[(mfL * 16 + quad * 4 + rr) * 260 + wc * 64 + nf * 16 + lrow] =
                acc[mh + mfL][nf][rr] + bv[nf];
    }
    __syncthreads();
#pragma unroll
    for (int k = 0; k < 8; ++k) {
      const int lr = wid * 8 + k;
      const long grow = m0 + ch * 64 + lr;
      float2 v0 = *(const float2*)&sc[lr * 260 + lane * 2];
      float2 v1 = *(const float2*)&sc[lr * 260 + 128 + lane * 2];
      const long rb = grow * (long)N_VOCAB;
      const int ca = n0 + lane * 2;
      const int cb = ca + 128;
      if (ca + 1 < N_VOCAB)      *(float2*)&out[rb + ca] = v0;
      else if (ca < N_VOCAB)     out[rb + ca] = v0.x;
      if (cb + 1 < N_VOCAB)      *(float2*)&out[rb + cb] = v1;
      else if (cb < N_VOCAB)     out[rb + cb] = v1.x;
    }
  }
}

#undef DSREAD_B
#undef DSREAD_A
#undef MFMA_Q
#undef BAR_SB
#undef LGKM0

// ---------------- IOU combine: one wave per (b,s,t) ----------------
__global__ __launch_bounds__(256) void iou_combine(const float* __restrict__ Xcat,
                                                   const float* __restrict__ b1,
                                                   const float* __restrict__ w2,
                                                   const float* __restrict__ b2,
                                                   float* __restrict__ out) {
  int gw = (blockIdx.x * 256 + threadIdx.x) >> 6;
  int lane = threadIdx.x & 63;
  if (gw >= 32 * 32 * 33) return;
  int b = gw / 1056;
  int rem = gw % 1056;
  int s = rem / 33;
  int t = rem % 33;
  int cidx = (s + t) >> 1;
  const float* ps = Xcat + (long)(b * 33 + s) * N_IOU;
  const float* pc = Xcat + (long)(b * 33 + cidx) * N_IOU + 768;
  const float* pe = Xcat + (long)(b * 33 + t) * N_IOU + 1536;
  float a0 = 0.f, a1 = 0.f, a2 = 0.f;
#pragma unroll
  for (int j = 0; j < 3; ++j) {
    int h0 = j * 256 + lane * 4;
    float4 vs = *(const float4*)(ps + h0);
    float4 vc = *(const float4*)(pc + h0);
    float4 ve = *(const float4*)(pe + h0);
    float4 vb = *(const float4*)(b1 + h0);
    const float* fs = (const float*)&vs;
    const float* fc = (const float*)&vc;
    const float* fe = (const float*)&ve;
    const float* fb = (const float*)&vb;
#pragma unroll
    for (int c = 0; c < 4; ++c) {
      float v = fmaxf(fs[c] + fc[c] + fe[c] + fb[c], 0.f);
      int h = h0 + c;
      a0 += v * w2[h * 3 + 0];
      a1 += v * w2[h * 3 + 1];
      a2 += v * w2[h * 3 + 2];
    }
  }
#pragma unroll
  for (int off = 32; off > 0; off >>= 1) {
    a0 += __shfl_down(a0, off, 64);
    a1 += __shfl_down(a1, off, 64);
    a2 += __shfl_down(a2, off, 64);
  }
  if (lane == 0) {
    int base = OUT_IOU_OFF + b * 3168 + s * 33 + t;   // ((b*3+k)*32+s)*33+t
    out[base + 0 * 1056] = a0 + b2[0];
    out[base + 1 * 1056] = a1 + b2[1];
    out[base + 2 * 1056] = a2 + b2[2];
  }
}

extern "C" void kernel_launch(void* const* d_in, const int* in_sizes, int n_in,
                              void* d_out, int out_size, void* d_ws, size_t ws_size,
                              hipStream_t stream) {
  const float* hst  = (const float*)d_in[0];  // (32,48,768)
  const float* hso  = (const float*)d_in[1];  // (32,33,768)
  const float* w_t1 = (const float*)d_in[2];  // (768,768)
  const float* b_t1 = (const float*)d_in[3];  // (768,)
  const float* w_t2 = (const float*)d_in[4];  // (768,30522)
  const float* b_t2 = (const float*)d_in[5];  // (30522,)
  const float* w_i1 = (const float*)d_in[6];  // (2304,768)
  const float* b_i1 = (const float*)d_in[7];  // (768,)
  const float* w_i2 = (const float*)d_in[8];  // (768,3)
  const float* b_i2 = (const float*)d_in[9];  // (3,)
  float* out = (float*)d_out;

  // workspace layout (bytes) — unchanged, end 68,812,800
  char* ws = (char*)d_ws;
  u16*   w_t2T = (u16*)(ws + 0);           // 30592*768*2 = 46,989,312
  u16*   xt    = (u16*)(ws + 46989312);    //  1536*768*2 =  2,359,296
  u16*   w_t1T = (u16*)(ws + 49348608);    //   768*768*2 =  1,179,648
  u16*   htext = (u16*)(ws + 50528256);    //  1536*768*2 =  2,359,296
  u16*   hcb   = (u16*)(ws + 52887552);    //  1152*768*2 =  1,769,472
  u16*   w_i1T = (u16*)(ws + 54657024);    //  2304*768*2 =  3,538,944
  float* Xcat  = (float*)(ws + 58195968);  // 1152*2304*4 = 10,616,832

  // 1) conversions / transposes / mask
  prep_cvt<<<dim3(2016), dim3(256), 0, stream>>>(hst, hso, xt, hcb);
  transpose_cvt<<<dim3(12, 12, 1), dim3(256), 0, stream>>>(w_t1, w_t1T, 768, 0, 0);
  transpose_cvt<<<dim3(12, N_VOCAB_PAD / 64, 1), dim3(256), 0, stream>>>(w_t2, w_t2T, N_VOCAB, 0, 0);
  transpose_cvt<<<dim3(12, 12, 3), dim3(256), 0, stream>>>(w_i1, w_i1T, 768, 768L * 768, 768L * 768);
  mask_kernel<<<dim3(5), dim3(256), 0, stream>>>(out);

  // 2) text path
  gemm_bt<1><<<dim3(KDIM / 128, M_TEXT / 128), dim3(256), 0, stream>>>(
      xt, w_t1T, nullptr, htext, b_t1, KDIM, KDIM);
  gemm_big<<<dim3(720), dim3(512), 0, stream>>>(htext, w_t2T, out, b_t2);

  // 3) iou path
  gemm_bt<2><<<dim3(N_IOU / 128, M_HC_PAD / 128), dim3(256), 0, stream>>>(
      hcb, w_i1T, Xcat, nullptr, nullptr, N_IOU, N_IOU);
  iou_combine<<<dim3(8448), dim3(256), 0, stream>>>(Xcat, b_i1, w_i2, b_i2, out);
}

// Round 3
// 524.607 us; speedup vs baseline: 1.0407x; 1.0407x over previous
//
#include <hip/hip_runtime.h>

typedef unsigned short u16;
typedef short v8s __attribute__((ext_vector_type(8)));
typedef float v4f __attribute__((ext_vector_type(4)));
typedef float v2f __attribute__((ext_vector_type(2)));

// ---- problem constants ----
#define KDIM 768
#define M_TEXT 1536            // 32*48
#define N_VOCAB 30522
#define N_VOCAB_PAD 30592      // 239*128 (B buffer rows; zero-padded 30522..30591)
#define M_HC 1056              // 32*33
#define M_HC_PAD 1152          // 9*128
#define N_IOU 2304             // 3*768
#define OUT_IOU_OFF 46881792
#define OUT_MASK_OFF 46983168

__device__ __forceinline__ u16 f2bf(float f) {
  unsigned u = __float_as_uint(f);
  u += 0x7fffu + ((u >> 16) & 1u);   // RNE
  return (u16)(u >> 16);
}

// ------- prep: convert activations to bf16 (hc padded to 1152 rows) + mask map -------
__global__ __launch_bounds__(256) void prep_cvt(const float* __restrict__ xt_in,
                                                const float* __restrict__ hc_in,
                                                u16* __restrict__ xt,
                                                u16* __restrict__ hcb,
                                                float* __restrict__ out) {
  const int NXT = M_TEXT * KDIM / 4;      // 294912 float4s
  if (blockIdx.x >= 2016) {               // folded mask_kernel (blocks 2016..2020)
    int idx = (blockIdx.x - 2016) * 256 + threadIdx.x;
    if (idx >= 1056) return;
    int i = idx / 33, j = idx % 33;
    float v = 0.f;
    int hi = min(i + 17, 33);
    if (j >= i + 1 && j < hi) v = 1.f;
    if ((i & 1) == 0 && i < 16 && j >= 18 + i && ((j - (18 + i)) & 1) == 0) v = 1.f;
    out[OUT_MASK_OFF + idx] = v;
    return;
  }
  int i = blockIdx.x * 256 + threadIdx.x; // < 516096 = (294912+221184)
  if (i < NXT) {
    float4 v = ((const float4*)xt_in)[i];
    ushort4 o; o.x = f2bf(v.x); o.y = f2bf(v.y); o.z = f2bf(v.z); o.w = f2bf(v.w);
    ((ushort4*)xt)[i] = o;
  } else {
    int j = i - NXT;                      // < 1152*192
    int row = j / 192;
    float4 v = make_float4(0.f, 0.f, 0.f, 0.f);
    if (row < M_HC) v = ((const float4*)hc_in)[j];
    ushort4 o; o.x = f2bf(v.x); o.y = f2bf(v.y); o.z = f2bf(v.z); o.w = f2bf(v.w);
    ((ushort4*)hcb)[j] = o;
  }
}

// ---------------- transpose + convert: in fp32 (768 x C) -> out bf16 (Cpad x 768) --------
__global__ __launch_bounds__(256) void transpose_cvt(const float* __restrict__ in,
                                                     u16* __restrict__ out,
                                                     int C, long inBatch, long outBatch) {
  __shared__ float tile[64][65];
  const float* ip = in + (long)blockIdx.z * inBatch;
  u16* op = out + (long)blockIdx.z * outBatch;
  int r0 = blockIdx.x * 64, c0 = blockIdx.y * 64;
  int tx = threadIdx.x & 63, tg = threadIdx.x >> 6;
#pragma unroll
  for (int i = 0; i < 16; ++i) {
    int r = tg + i * 4;
    int gc = c0 + tx;
    tile[r][tx] = (gc < C) ? ip[(long)(r0 + r) * C + gc] : 0.f;
  }
  __syncthreads();
#pragma unroll
  for (int i = 0; i < 16; ++i) {
    int cc = tg + i * 4;
    op[(long)(c0 + cc) * KDIM + r0 + tx] = f2bf(tile[tx][cc]);
  }
}

// ---------------- m97-style 128^2 GEMM (kept for the two small GEMMs) ----------------
// MODE 1: bfout = bf16(relu(acc + bias[c])), ldc
// MODE 2: fout = acc (no bias, no guard), ldc
template <int MODE>
__global__ __launch_bounds__(256)
void gemm_bt(const u16* __restrict__ A, const u16* __restrict__ BT,
             float* __restrict__ fout, u16* __restrict__ bfout,
             const float* __restrict__ bias, int ldc, int nmax) {
  __shared__ u16 sA[128 * 32];
  __shared__ u16 sB[128 * 32];
  const int tid = threadIdx.x;
  const int wid = tid >> 6;
  const int lane = tid & 63;
  const int lrow = lane & 15;
  const int quad = lane >> 4;
  const int wm = (wid & 1) * 64;
  const int wn = (wid >> 1) * 64;
  const int m0 = blockIdx.y * 128;
  const int n0 = blockIdx.x * 128;

  const int srow = wid * 32 + (lane >> 2);
  const int scol = (lane & 3) * 8;
  const u16* gA = A + (long)(m0 + srow) * KDIM + scol;
  const u16* gB = BT + (long)(n0 + srow) * KDIM + scol;
  u16* lA = &sA[(wid * 32) * 32];
  u16* lB = &sB[(wid * 32) * 32];

  v4f acc[4][4];
#pragma unroll
  for (int i = 0; i < 4; ++i)
#pragma unroll
    for (int j = 0; j < 4; ++j) acc[i][j] = (v4f){0.f, 0.f, 0.f, 0.f};

  const v8s* pA = (const v8s*)sA;
  const v8s* pB = (const v8s*)sB;
  const int ia0 = (wm + lrow) * 4 + quad;
  const int ib0 = (wn + lrow) * 4 + quad;

  for (int kt = 0; kt < KDIM / 32; ++kt) {
    const u16* ga = gA + kt * 32;
    const u16* gb = gB + kt * 32;
    __builtin_amdgcn_global_load_lds((const __attribute__((address_space(1))) void*)ga,
                                     (__attribute__((address_space(3))) void*)lA, 16, 0, 0);
    __builtin_amdgcn_global_load_lds((const __attribute__((address_space(1))) void*)(ga + 16 * KDIM),
                                     (__attribute__((address_space(3))) void*)(lA + 16 * 32), 16, 0, 0);
    __builtin_amdgcn_global_load_lds((const __attribute__((address_space(1))) void*)gb,
                                     (__attribute__((address_space(3))) void*)lB, 16, 0, 0);
    __builtin_amdgcn_global_load_lds((const __attribute__((address_space(1))) void*)(gb + 16 * KDIM),
                                     (__attribute__((address_space(3))) void*)(lB + 16 * 32), 16, 0, 0);
    __syncthreads();

    v8s af[4], bfr[4];
#pragma unroll
    for (int mt = 0; mt < 4; ++mt) af[mt] = pA[ia0 + mt * 64];
#pragma unroll
    for (int nt = 0; nt < 4; ++nt) bfr[nt] = pB[ib0 + nt * 64];
#pragma unroll
    for (int mt = 0; mt < 4; ++mt)
#pragma unroll
      for (int nt = 0; nt < 4; ++nt)
        acc[mt][nt] = __builtin_amdgcn_mfma_f32_16x16x32_bf16(af[mt], bfr[nt], acc[mt][nt], 0, 0, 0);
    __syncthreads();
  }

#pragma unroll
  for (int nt = 0; nt < 4; ++nt) {
    int c = n0 + wn + nt * 16 + lrow;
    float bv = 0.f;
    if (MODE == 1) bv = bias[c];
#pragma unroll
    for (int mt = 0; mt < 4; ++mt) {
#pragma unroll
      for (int r = 0; r < 4; ++r) {
        int row = m0 + wm + mt * 16 + quad * 4 + r;
        float v = acc[mt][nt][r] + bv;
        if (MODE == 1) {
          bfout[(long)row * ldc + c] = f2bf(fmaxf(v, 0.f));
        } else {
          fout[(long)row * ldc + c] = v;
        }
      }
    }
  }
}

// ================= big vocab GEMM: 256x256 tile, 8 waves, BK=64, 8-phase =================
// C[1536, 30522(+pad)] = htext[1536,768] * w_t2T[30592,768]^T + bias
// Loop: unchanged (verified). Epilogue: LDS-staged coalesced rows, NONTEMPORAL stores
// (nt = no write-allocate / no RMW fetch / no L2 thrash; output is never re-read).
#define DSREAD_B(sB) do {                                                  \
    const u16* _b = (sB) + bBase;                                          \
    _Pragma("unroll")                                                      \
    for (int _nf = 0; _nf < 4; ++_nf) {                                    \
      bfr[_nf][0] = *(const v8s*)(_b + _nf * 1024 + c0);                   \
      bfr[_nf][1] = *(const v8s*)(_b + _nf * 1024 + c1);                   \
    } } while (0)

#define DSREAD_A(sA, q) do {                                               \
    const u16* _a = (sA) + aBase + (q) * 2048;                             \
    af[0][0] = *(const v8s*)(_a + c0);                                     \
    af[0][1] = *(const v8s*)(_a + c1);                                     \
    af[1][0] = *(const v8s*)(_a + 1024 + c0);                              \
    af[1][1] = *(const v8s*)(_a + 1024 + c1);                              \
  } while (0)

#define MFMA_Q(q) do {                                                     \
    _Pragma("unroll")                                                      \
    for (int _m = 0; _m < 2; ++_m)                                         \
      _Pragma("unroll")                                                    \
      for (int _nf = 0; _nf < 4; ++_nf) {                                  \
        acc[2*(q)+_m][_nf] = __builtin_amdgcn_mfma_f32_16x16x32_bf16(      \
            af[_m][0], bfr[_nf][0], acc[2*(q)+_m][_nf], 0, 0, 0);          \
        acc[2*(q)+_m][_nf] = __builtin_amdgcn_mfma_f32_16x16x32_bf16(      \
            af[_m][1], bfr[_nf][1], acc[2*(q)+_m][_nf], 0, 0, 0);          \
      } } while (0)

#define BAR_SB() do { __builtin_amdgcn_s_barrier();                        \
                      __builtin_amdgcn_sched_barrier(0); } while (0)
#define LGKM0() do { asm volatile("s_waitcnt lgkmcnt(0)" ::: "memory");    \
                     __builtin_amdgcn_sched_barrier(0); } while (0)

__global__ __launch_bounds__(512, 2)
void gemm_big(const u16* __restrict__ A, const u16* __restrict__ BT,
              float* __restrict__ out, const float* __restrict__ bias) {
  __shared__ u16 sbuf[2][2][256 * 64];   // [buf][0=A,1=B], 128 KiB total

  // T1: XCD-chunked, M-fastest remap. 720 blocks, 8 XCDs, chunk = 90.
  const int id = blockIdx.x;
  const int swz = (id & 7) * 90 + (id >> 3);
  const int mt = swz % 6;
  const int nt = swz / 6;
  const int m0 = mt * 256, n0 = nt * 256;

  const int tid = threadIdx.x;
  const int wid = tid >> 6;
  const int lane = tid & 63;
  const int l3 = lane >> 3;            // 0..7 (row within 8-row chunk)
  const int l7 = lane & 7;
  const int lrow = lane & 15;
  const int quad = lane >> 4;
  const int wr = wid >> 2;             // 0..1  -> wave's 128-row half of M
  const int wc = wid & 3;              // 0..3  -> wave's 64-col slice of N

  // staging: pre-swizzled global source, linear LDS dest (rule #21)
  const int xc = (l7 ^ l3) * 8;        // swizzled K column (elements)
  const u16* Ag = A  + (long)(m0 + wid * 16 + l3) * KDIM + xc;
  const u16* Bg = BT + (long)(n0 + wid * 16 + l3) * KDIM + xc;

  u16* const sA0 = &sbuf[0][0][0];
  u16* const sB0 = &sbuf[0][1][0];
  u16* const sA1 = &sbuf[1][0][0];
  u16* const sB1 = &sbuf[1][1][0];

  auto stageA = [&](u16* sdst, int kt, int h) {
#pragma unroll
    for (int j = 0; j < 2; ++j)
      __builtin_amdgcn_global_load_lds(
          (const __attribute__((address_space(1))) void*)(Ag + (long)kt * 64 +
                                                          (long)((h * 128 + j * 8) * KDIM)),
          (__attribute__((address_space(3))) void*)(sdst + (h * 128 + wid * 16 + j * 8) * 64),
          16, 0, 0);
  };
  auto stageB = [&](u16* sdst, int kt, int h) {
    // last N-tile: rows >= 30592 don't exist; clamp source (cols >= 30522 never stored)
    const int hh = (n0 + h * 128 >= N_VOCAB_PAD) ? 0 : h;
#pragma unroll
    for (int j = 0; j < 2; ++j)
      __builtin_amdgcn_global_load_lds(
          (const __attribute__((address_space(1))) void*)(Bg + (long)kt * 64 +
                                                          (long)((hh * 128 + j * 8) * KDIM)),
          (__attribute__((address_space(3))) void*)(sdst + (h * 128 + wid * 16 + j * 8) * 64),
          16, 0, 0);
  };

  // ds_read fragment addressing (swizzled): elem = row*64 + ((ks*32+quad*8) ^ (row&7)*8)
  const int aBase = (wr * 128 + lrow) * 64;
  const int bBase = (wc * 64 + lrow) * 64;
  const int xls = (lrow & 7) * 8;
  const int c0 = (quad * 8) ^ xls;
  const int c1 = c0 ^ 32;

  v4f acc[8][4];
#pragma unroll
  for (int i = 0; i < 8; ++i)
#pragma unroll
    for (int j = 0; j < 4; ++j) acc[i][j] = (v4f){0.f, 0.f, 0.f, 0.f};

  v8s bfr[4][2];
  v8s af[2][2];

  // ---- prologue: b0 (k=0) fully + b1.B (k=1); b1.A(k=1) staged in iter0 ph1/2 ----
  stageA(sA0, 0, 0); stageA(sA0, 0, 1);
  stageB(sB0, 0, 0); stageB(sB0, 0, 1);
  stageB(sB1, 1, 0); stageB(sB1, 1, 1);
  asm volatile("s_waitcnt vmcnt(4)" ::: "memory");   // b0's 8 loads done, b1.B in flight
  __builtin_amdgcn_sched_barrier(0);
  BAR_SB();

#pragma unroll 1
  for (int it = 0; it < 6; ++it) {
    const int kA1 = 2 * it + 1;        // b1.A target (always valid)
    const int kB0 = 2 * it + 2;        // b0 target
    const int kB1 = 2 * it + 3;        // b1.B target
    const bool more = (it < 5);

    // ---- PH1 (buf0, quad0): read all B-frags + A q0; stage b1.A h0 ----
    DSREAD_B(sB0);
    DSREAD_A(sA0, 0);
    stageA(sA1, kA1, 0);
    __builtin_amdgcn_s_barrier();
    LGKM0();
    __builtin_amdgcn_s_setprio(1); MFMA_Q(0); __builtin_amdgcn_s_setprio(0);
    BAR_SB();

    // ---- PH2 ----
    DSREAD_A(sA0, 1);
    stageA(sA1, kA1, 1);
    __builtin_amdgcn_s_barrier();
    LGKM0();
    __builtin_amdgcn_s_setprio(1); MFMA_Q(1); __builtin_amdgcn_s_setprio(0);
    BAR_SB();

    // ---- PH3 ----
    DSREAD_A(sA0, 2);
    if (more) stageB(sB0, kB0, 0);
    __builtin_amdgcn_s_barrier();
    LGKM0();
    __builtin_amdgcn_s_setprio(1); MFMA_Q(2); __builtin_amdgcn_s_setprio(0);
    BAR_SB();

    // ---- PH4: counted wait (b1.B[prev] + b1.A h0/h1 must be resident for PH5) ----
    DSREAD_A(sA0, 3);
    if (more) stageB(sB0, kB0, 1);
    __builtin_amdgcn_s_barrier();
    LGKM0();
    __builtin_amdgcn_s_setprio(1); MFMA_Q(3); __builtin_amdgcn_s_setprio(0);
    if (more) { asm volatile("s_waitcnt vmcnt(4)" ::: "memory"); }
    else      { asm volatile("s_waitcnt vmcnt(0)" ::: "memory"); }
    __builtin_amdgcn_sched_barrier(0);
    BAR_SB();

    // ---- PH5 (buf1, quad0): read all B-frags + A q0; stage b0.A h0 ----
    DSREAD_B(sB1);
    DSREAD_A(sA1, 0);
    if (more) stageA(sA0, kB0, 0);
    __builtin_amdgcn_s_barrier();
    LGKM0();
    __builtin_amdgcn_s_setprio(1); MFMA_Q(0); __builtin_amdgcn_s_setprio(0);
    BAR_SB();

    // ---- PH6 ----
    DSREAD_A(sA1, 1);
    if (more) stageA(sA0, kB0, 1);
    __builtin_amdgcn_s_barrier();
    LGKM0();
    __builtin_amdgcn_s_setprio(1); MFMA_Q(1); __builtin_amdgcn_s_setprio(0);
    BAR_SB();

    // ---- PH7 ----
    DSREAD_A(sA1, 2);
    if (more) stageB(sB1, kB1, 0);
    __builtin_amdgcn_s_barrier();
    LGKM0();
    __builtin_amdgcn_s_setprio(1); MFMA_Q(2); __builtin_amdgcn_s_setprio(0);
    BAR_SB();

    // ---- PH8: counted wait (b0.B + b0.A must be resident for next PH1) ----
    DSREAD_A(sA1, 3);
    if (more) stageB(sB1, kB1, 1);
    __builtin_amdgcn_s_barrier();
    LGKM0();
    __builtin_amdgcn_s_setprio(1); MFMA_Q(3); __builtin_amdgcn_s_setprio(0);
    if (more) { asm volatile("s_waitcnt vmcnt(4)" ::: "memory");
                __builtin_amdgcn_sched_barrier(0); }
    BAR_SB();
  }

  // ---- epilogue: LDS-staged coalesced row stores (nontemporal) ----
  float* sc = (float*)&sbuf[0][0][0];    // 64*260*4 = 66,560 B < 128 KiB
  float bv[4];
#pragma unroll
  for (int nf = 0; nf < 4; ++nf) {
    int col = n0 + wc * 64 + nf * 16 + lrow;
    bv[nf] = (col < N_VOCAB) ? bias[col] : 0.f;
  }
#pragma unroll 1
  for (int ch = 0; ch < 4; ++ch) {
    __syncthreads();
    if (wr == (ch >> 1)) {
      const int mh = (ch & 1) * 4;
#pragma unroll
      for (int mfL = 0; mfL < 4; ++mfL)
#pragma unroll
        for (int nf = 0; nf < 4; ++nf)
#pragma unroll
          for (int rr = 0; rr < 4; ++rr)
            sc[(mfL * 16 + quad * 4 + rr) * 260 + wc * 64 + nf * 16 + lrow] =
                acc[mh + mfL][nf][rr] + bv[nf];
    }
    __syncthreads();
#pragma unroll
    for (int k = 0; k < 8; ++k) {
      const int lr = wid * 8 + k;
      const long grow = m0 + ch * 64 + lr;
      v2f v0 = *(const v2f*)&sc[lr * 260 + lane * 2];
      v2f v1 = *(const v2f*)&sc[lr * 260 + 128 + lane * 2];
      const long rb = grow * (long)N_VOCAB;
      const int ca = n0 + lane * 2;
      const int cb = ca + 128;
      if (ca + 1 < N_VOCAB)      __builtin_nontemporal_store(v0, (v2f*)&out[rb + ca]);
      else if (ca < N_VOCAB)     __builtin_nontemporal_store(v0[0], &out[rb + ca]);
      if (cb + 1 < N_VOCAB)      __builtin_nontemporal_store(v1, (v2f*)&out[rb + cb]);
      else if (cb < N_VOCAB)     __builtin_nontemporal_store(v1[0], &out[rb + cb]);
    }
  }
}

#undef DSREAD_B
#undef DSREAD_A
#undef MFMA_Q
#undef BAR_SB
#undef LGKM0

// ---------------- IOU combine: one wave per (b,s,t) ----------------
__global__ __launch_bounds__(256) void iou_combine(const float* __restrict__ Xcat,
                                                   const float* __restrict__ b1,
                                                   const float* __restrict__ w2,
                                                   const float* __restrict__ b2,
                                                   float* __restrict__ out) {
  int gw = (blockIdx.x * 256 + threadIdx.x) >> 6;
  int lane = threadIdx.x & 63;
  if (gw >= 32 * 32 * 33) return;
  int b = gw / 1056;
  int rem = gw % 1056;
  int s = rem / 33;
  int t = rem % 33;
  int cidx = (s + t) >> 1;
  const float* ps = Xcat + (long)(b * 33 + s) * N_IOU;
  const float* pc = Xcat + (long)(b * 33 + cidx) * N_IOU + 768;
  const float* pe = Xcat + (long)(b * 33 + t) * N_IOU + 1536;
  float a0 = 0.f, a1 = 0.f, a2 = 0.f;
#pragma unroll
  for (int j = 0; j < 3; ++j) {
    int h0 = j * 256 + lane * 4;
    float4 vs = *(const float4*)(ps + h0);
    float4 vc = *(const float4*)(pc + h0);
    float4 ve = *(const float4*)(pe + h0);
    float4 vb = *(const float4*)(b1 + h0);
    const float* fs = (const float*)&vs;
    const float* fc = (const float*)&vc;
    const float* fe = (const float*)&ve;
    const float* fb = (const float*)&vb;
#pragma unroll
    for (int c = 0; c < 4; ++c) {
      float v = fmaxf(fs[c] + fc[c] + fe[c] + fb[c], 0.f);
      int h = h0 + c;
      a0 += v * w2[h * 3 + 0];
      a1 += v * w2[h * 3 + 1];
      a2 += v * w2[h * 3 + 2];
    }
  }
#pragma unroll
  for (int off = 32; off > 0; off >>= 1) {
    a0 += __shfl_down(a0, off, 64);
    a1 += __shfl_down(a1, off, 64);
    a2 += __shfl_down(a2, off, 64);
  }
  if (lane == 0) {
    int base = OUT_IOU_OFF + b * 3168 + s * 33 + t;   // ((b*3+k)*32+s)*33+t
    out[base + 0 * 1056] = a0 + b2[0];
    out[base + 1 * 1056] = a1 + b2[1];
    out[base + 2 * 1056] = a2 + b2[2];
  }
}

extern "C" void kernel_launch(void* const* d_in, const int* in_sizes, int n_in,
                              void* d_out, int out_size, void* d_ws, size_t ws_size,
                              hipStream_t stream) {
  const float* hst  = (const float*)d_in[0];  // (32,48,768)
  const float* hso  = (const float*)d_in[1];  // (32,33,768)
  const float* w_t1 = (const float*)d_in[2];  // (768,768)
  const float* b_t1 = (const float*)d_in[3];  // (768,)
  const float* w_t2 = (const float*)d_in[4];  // (768,30522)
  const float* b_t2 = (const float*)d_in[5];  // (30522,)
  const float* w_i1 = (const float*)d_in[6];  // (2304,768)
  const float* b_i1 = (const float*)d_in[7];  // (768,)
  const float* w_i2 = (const float*)d_in[8];  // (768,3)
  const float* b_i2 = (const float*)d_in[9];  // (3,)
  float* out = (float*)d_out;

  // workspace layout (bytes) — unchanged, end 68,812,800
  char* ws = (char*)d_ws;
  u16*   w_t2T = (u16*)(ws + 0);           // 30592*768*2 = 46,989,312
  u16*   xt    = (u16*)(ws + 46989312);    //  1536*768*2 =  2,359,296
  u16*   w_t1T = (u16*)(ws + 49348608);    //   768*768*2 =  1,179,648
  u16*   htext = (u16*)(ws + 50528256);    //  1536*768*2 =  2,359,296
  u16*   hcb   = (u16*)(ws + 52887552);    //  1152*768*2 =  1,769,472
  u16*   w_i1T = (u16*)(ws + 54657024);    //  2304*768*2 =  3,538,944
  float* Xcat  = (float*)(ws + 58195968);  // 1152*2304*4 = 10,616,832

  // 1) conversions / transposes / mask (mask folded into prep_cvt)
  prep_cvt<<<dim3(2021), dim3(256), 0, stream>>>(hst, hso, xt, hcb, out);
  transpose_cvt<<<dim3(12, 12, 1), dim3(256), 0, stream>>>(w_t1, w_t1T, 768, 0, 0);
  transpose_cvt<<<dim3(12, N_VOCAB_PAD / 64, 1), dim3(256), 0, stream>>>(w_t2, w_t2T, N_VOCAB, 0, 0);
  transpose_cvt<<<dim3(12, 12, 3), dim3(256), 0, stream>>>(w_i1, w_i1T, 768, 768L * 768, 768L * 768);

  // 2) text path
  gemm_bt<1><<<dim3(KDIM / 128, M_TEXT / 128), dim3(256), 0, stream>>>(
      xt, w_t1T, nullptr, htext, b_t1, KDIM, KDIM);
  gemm_big<<<dim3(720), dim3(512), 0, stream>>>(htext, w_t2T, out, b_t2);

  // 3) iou path
  gemm_bt<2><<<dim3(N_IOU / 128, M_HC_PAD / 128), dim3(256), 0, stream>>>(
      hcb, w_i1T, Xcat, nullptr, nullptr, N_IOU, N_IOU);
  iou_combine<<<dim3(8448), dim3(256), 0, stream>>>(Xcat, b_i1, w_i2, b_i2, out);
}

// Round 4
// 506.902 us; speedup vs baseline: 1.0771x; 1.0349x over previous
//
#include <hip/hip_runtime.h>

typedef unsigned short u16;
typedef short v8s __attribute__((ext_vector_type(8)));
typedef float v4f __attribute__((ext_vector_type(4)));

// ---- problem constants ----
#define KDIM 768
#define M_TEXT 1536            // 32*48
#define N_VOCAB 30522
#define N_VOCAB_PAD 30592      // 239*128 (B buffer rows; zero-padded 30522..30591)
#define M_HC 1056              // 32*33
#define M_HC_PAD 1152          // 9*128
#define N_IOU 2304             // 3*768
#define OUT_IOU_OFF 46881792
#define OUT_MASK_OFF 46983168

__device__ __forceinline__ u16 f2bf(float f) {
  unsigned u = __float_as_uint(f);
  u += 0x7fffu + ((u >> 16) & 1u);   // RNE
  return (u16)(u >> 16);
}

// ------- prep: convert activations to bf16 (hc padded to 1152 rows) + mask map -------
__global__ __launch_bounds__(256) void prep_cvt(const float* __restrict__ xt_in,
                                                const float* __restrict__ hc_in,
                                                u16* __restrict__ xt,
                                                u16* __restrict__ hcb,
                                                float* __restrict__ out) {
  const int NXT = M_TEXT * KDIM / 4;      // 294912 float4s
  if (blockIdx.x >= 2016) {               // folded mask_kernel (blocks 2016..2020)
    int idx = (blockIdx.x - 2016) * 256 + threadIdx.x;
    if (idx >= 1056) return;
    int i = idx / 33, j = idx % 33;
    float v = 0.f;
    int hi = min(i + 17, 33);
    if (j >= i + 1 && j < hi) v = 1.f;
    if ((i & 1) == 0 && i < 16 && j >= 18 + i && ((j - (18 + i)) & 1) == 0) v = 1.f;
    out[OUT_MASK_OFF + idx] = v;
    return;
  }
  int i = blockIdx.x * 256 + threadIdx.x; // < 516096 = (294912+221184)
  if (i < NXT) {
    float4 v = ((const float4*)xt_in)[i];
    ushort4 o; o.x = f2bf(v.x); o.y = f2bf(v.y); o.z = f2bf(v.z); o.w = f2bf(v.w);
    ((ushort4*)xt)[i] = o;
  } else {
    int j = i - NXT;                      // < 1152*192
    int row = j / 192;
    float4 v = make_float4(0.f, 0.f, 0.f, 0.f);
    if (row < M_HC) v = ((const float4*)hc_in)[j];
    ushort4 o; o.x = f2bf(v.x); o.y = f2bf(v.y); o.z = f2bf(v.z); o.w = f2bf(v.w);
    ((ushort4*)hcb)[j] = o;
  }
}

// ------- merged transpose + convert: all three weight transposes in ONE launch -------
// block roles: [0,144) w_t1 (12x12, C=768); [144,5880) w_t2 (12x478, C=30522);
//              [5880,6312) w_i1 (3 batches of 12x12, C=768)
__global__ __launch_bounds__(256) void transpose_all(const float* __restrict__ w_t1,
                                                     u16* __restrict__ w_t1T,
                                                     const float* __restrict__ w_t2,
                                                     u16* __restrict__ w_t2T,
                                                     const float* __restrict__ w_i1,
                                                     u16* __restrict__ w_i1T) {
  __shared__ float tile[64][65];
  int b = blockIdx.x;
  const float* ip; u16* op; int C, bx, by;
  if (b < 144) {
    ip = w_t1; op = w_t1T; C = 768; bx = b % 12; by = b / 12;
  } else if (b < 5880) {
    int r = b - 144; ip = w_t2; op = w_t2T; C = N_VOCAB; bx = r % 12; by = r / 12;
  } else {
    int r = b - 5880; int z = r / 144; int q = r % 144;
    ip = w_i1 + (long)z * 768 * 768; op = w_i1T + (long)z * 768 * 768;
    C = 768; bx = q % 12; by = q / 12;
  }
  int r0 = bx * 64, c0 = by * 64;
  int tx = threadIdx.x & 63, tg = threadIdx.x >> 6;
#pragma unroll
  for (int i = 0; i < 16; ++i) {
    int r = tg + i * 4;
    int gc = c0 + tx;
    tile[r][tx] = (gc < C) ? ip[(long)(r0 + r) * C + gc] : 0.f;
  }
  __syncthreads();
#pragma unroll
  for (int i = 0; i < 16; ++i) {
    int cc = tg + i * 4;
    op[(long)(c0 + cc) * KDIM + r0 + tx] = f2bf(tile[tx][cc]);
  }
}

// ------- merged small GEMMs: text (MODE1, 72 blocks) + iou (MODE2, 162 blocks) -------
// m97-style 128^2 tile, 4 waves. One launch fills CUs instead of two serial launches.
__global__ __launch_bounds__(256)
void gemm_small(const u16* __restrict__ xt, const u16* __restrict__ w_t1T,
                u16* __restrict__ htext, const float* __restrict__ b_t1,
                const u16* __restrict__ hcb, const u16* __restrict__ w_i1T,
                float* __restrict__ Xcat) {
  __shared__ u16 sA[128 * 32];
  __shared__ u16 sB[128 * 32];
  const int b = blockIdx.x;
  const u16 *A, *BT;
  float* fout = nullptr;
  u16* bfout = nullptr;
  const float* bias = nullptr;
  int mode, bx, by, ldc;
  if (b < 72) {            // text: relu(xt @ w_t1 + b_t1) -> bf16 htext; grid 6 x 12
    mode = 1; bx = b % 6; by = b / 6;
    A = xt; BT = w_t1T; bfout = htext; bias = b_t1; ldc = KDIM;
  } else {                 // iou: hcb @ w_i1 -> f32 Xcat; grid 18 x 9
    int r = b - 72;
    mode = 2; bx = r % 18; by = r / 18;
    A = hcb; BT = w_i1T; fout = Xcat; ldc = N_IOU;
  }
  const int tid = threadIdx.x;
  const int wid = tid >> 6;
  const int lane = tid & 63;
  const int lrow = lane & 15;
  const int quad = lane >> 4;
  const int wm = (wid & 1) * 64;
  const int wn = (wid >> 1) * 64;
  const int m0 = by * 128;
  const int n0 = bx * 128;

  const int srow = wid * 32 + (lane >> 2);
  const int scol = (lane & 3) * 8;
  const u16* gA = A + (long)(m0 + srow) * KDIM + scol;
  const u16* gB = BT + (long)(n0 + srow) * KDIM + scol;
  u16* lA = &sA[(wid * 32) * 32];
  u16* lB = &sB[(wid * 32) * 32];

  v4f acc[4][4];
#pragma unroll
  for (int i = 0; i < 4; ++i)
#pragma unroll
    for (int j = 0; j < 4; ++j) acc[i][j] = (v4f){0.f, 0.f, 0.f, 0.f};

  const v8s* pA = (const v8s*)sA;
  const v8s* pB = (const v8s*)sB;
  const int ia0 = (wm + lrow) * 4 + quad;
  const int ib0 = (wn + lrow) * 4 + quad;

  for (int kt = 0; kt < KDIM / 32; ++kt) {
    const u16* ga = gA + kt * 32;
    const u16* gb = gB + kt * 32;
    __builtin_amdgcn_global_load_lds((const __attribute__((address_space(1))) void*)ga,
                                     (__attribute__((address_space(3))) void*)lA, 16, 0, 0);
    __builtin_amdgcn_global_load_lds((const __attribute__((address_space(1))) void*)(ga + 16 * KDIM),
                                     (__attribute__((address_space(3))) void*)(lA + 16 * 32), 16, 0, 0);
    __builtin_amdgcn_global_load_lds((const __attribute__((address_space(1))) void*)gb,
                                     (__attribute__((address_space(3))) void*)lB, 16, 0, 0);
    __builtin_amdgcn_global_load_lds((const __attribute__((address_space(1))) void*)(gb + 16 * KDIM),
                                     (__attribute__((address_space(3))) void*)(lB + 16 * 32), 16, 0, 0);
    __syncthreads();

    v8s af[4], bfr[4];
#pragma unroll
    for (int mt = 0; mt < 4; ++mt) af[mt] = pA[ia0 + mt * 64];
#pragma unroll
    for (int nt = 0; nt < 4; ++nt) bfr[nt] = pB[ib0 + nt * 64];
#pragma unroll
    for (int mt = 0; mt < 4; ++mt)
#pragma unroll
      for (int nt = 0; nt < 4; ++nt)
        acc[mt][nt] = __builtin_amdgcn_mfma_f32_16x16x32_bf16(af[mt], bfr[nt], acc[mt][nt], 0, 0, 0);
    __syncthreads();
  }

#pragma unroll
  for (int nt = 0; nt < 4; ++nt) {
    int c = n0 + wn + nt * 16 + lrow;
    float bv = 0.f;
    if (mode == 1) bv = bias[c];
#pragma unroll
    for (int mt = 0; mt < 4; ++mt) {
#pragma unroll
      for (int r = 0; r < 4; ++r) {
        int row = m0 + wm + mt * 16 + quad * 4 + r;
        float v = acc[mt][nt][r] + bv;
        if (mode == 1) {
          bfout[(long)row * ldc + c] = f2bf(fmaxf(v, 0.f));
        } else {
          fout[(long)row * ldc + c] = v;
        }
      }
    }
  }
}

// ================= big vocab GEMM: 256x256 tile, 8 waves, BK=64, 8-phase =================
// C[1536, 30522(+pad)] = htext[1536,768] * w_t2T[30592,768]^T + bias
// Loop: verified round-1 structure. Epilogue: round-1 scattered stores (best measured:
// WRITE 292 MB vs 564 MB for LDS-staged variants — staged bursts amplify L2->HBM traffic).
#define DSREAD_B(sB) do {                                                  \
    const u16* _b = (sB) + bBase;                                          \
    _Pragma("unroll")                                                      \
    for (int _nf = 0; _nf < 4; ++_nf) {                                    \
      bfr[_nf][0] = *(const v8s*)(_b + _nf * 1024 + c0);                   \
      bfr[_nf][1] = *(const v8s*)(_b + _nf * 1024 + c1);                   \
    } } while (0)

#define DSREAD_A(sA, q) do {                                               \
    const u16* _a = (sA) + aBase + (q) * 2048;                             \
    af[0][0] = *(const v8s*)(_a + c0);                                     \
    af[0][1] = *(const v8s*)(_a + c1);                                     \
    af[1][0] = *(const v8s*)(_a + 1024 + c0);                              \
    af[1][1] = *(const v8s*)(_a + 1024 + c1);                              \
  } while (0)

#define MFMA_Q(q) do {                                                     \
    _Pragma("unroll")                                                      \
    for (int _m = 0; _m < 2; ++_m)                                         \
      _Pragma("unroll")                                                    \
      for (int _nf = 0; _nf < 4; ++_nf) {                                  \
        acc[2*(q)+_m][_nf] = __builtin_amdgcn_mfma_f32_16x16x32_bf16(      \
            af[_m][0], bfr[_nf][0], acc[2*(q)+_m][_nf], 0, 0, 0);          \
        acc[2*(q)+_m][_nf] = __builtin_amdgcn_mfma_f32_16x16x32_bf16(      \
            af[_m][1], bfr[_nf][1], acc[2*(q)+_m][_nf], 0, 0, 0);          \
      } } while (0)

#define BAR_SB() do { __builtin_amdgcn_s_barrier();                        \
                      __builtin_amdgcn_sched_barrier(0); } while (0)
#define LGKM0() do { asm volatile("s_waitcnt lgkmcnt(0)" ::: "memory");    \
                     __builtin_amdgcn_sched_barrier(0); } while (0)

__global__ __launch_bounds__(512, 2)
void gemm_big(const u16* __restrict__ A, const u16* __restrict__ BT,
              float* __restrict__ out, const float* __restrict__ bias) {
  __shared__ u16 sbuf[2][2][256 * 64];   // [buf][0=A,1=B], 128 KiB total

  // T1: XCD-chunked, M-fastest remap. 720 blocks, 8 XCDs, chunk = 90.
  const int id = blockIdx.x;
  const int swz = (id & 7) * 90 + (id >> 3);
  const int mt = swz % 6;
  const int nt = swz / 6;
  const int m0 = mt * 256, n0 = nt * 256;

  const int tid = threadIdx.x;
  const int wid = tid >> 6;
  const int lane = tid & 63;
  const int l3 = lane >> 3;            // 0..7 (row within 8-row chunk)
  const int l7 = lane & 7;
  const int lrow = lane & 15;
  const int quad = lane >> 4;
  const int wr = wid >> 2;             // 0..1  -> wave's 128-row half of M
  const int wc = wid & 3;              // 0..3  -> wave's 64-col slice of N

  // staging: pre-swizzled global source, linear LDS dest (rule #21)
  const int xc = (l7 ^ l3) * 8;        // swizzled K column (elements)
  const u16* Ag = A  + (long)(m0 + wid * 16 + l3) * KDIM + xc;
  const u16* Bg = BT + (long)(n0 + wid * 16 + l3) * KDIM + xc;

  u16* const sA0 = &sbuf[0][0][0];
  u16* const sB0 = &sbuf[0][1][0];
  u16* const sA1 = &sbuf[1][0][0];
  u16* const sB1 = &sbuf[1][1][0];

  auto stageA = [&](u16* sdst, int kt, int h) {
#pragma unroll
    for (int j = 0; j < 2; ++j)
      __builtin_amdgcn_global_load_lds(
          (const __attribute__((address_space(1))) void*)(Ag + (long)kt * 64 +
                                                          (long)((h * 128 + j * 8) * KDIM)),
          (__attribute__((address_space(3))) void*)(sdst + (h * 128 + wid * 16 + j * 8) * 64),
          16, 0, 0);
  };
  auto stageB = [&](u16* sdst, int kt, int h) {
    // last N-tile: rows >= 30592 don't exist; clamp source (cols >= 30522 never stored)
    const int hh = (n0 + h * 128 >= N_VOCAB_PAD) ? 0 : h;
#pragma unroll
    for (int j = 0; j < 2; ++j)
      __builtin_amdgcn_global_load_lds(
          (const __attribute__((address_space(1))) void*)(Bg + (long)kt * 64 +
                                                          (long)((hh * 128 + j * 8) * KDIM)),
          (__attribute__((address_space(3))) void*)(sdst + (h * 128 + wid * 16 + j * 8) * 64),
          16, 0, 0);
  };

  // ds_read fragment addressing (swizzled): elem = row*64 + ((ks*32+quad*8) ^ (row&7)*8)
  const int aBase = (wr * 128 + lrow) * 64;
  const int bBase = (wc * 64 + lrow) * 64;
  const int xls = (lrow & 7) * 8;
  const int c0 = (quad * 8) ^ xls;
  const int c1 = c0 ^ 32;

  v4f acc[8][4];
#pragma unroll
  for (int i = 0; i < 8; ++i)
#pragma unroll
    for (int j = 0; j < 4; ++j) acc[i][j] = (v4f){0.f, 0.f, 0.f, 0.f};

  v8s bfr[4][2];
  v8s af[2][2];

  // ---- prologue: b0 (k=0) fully + b1.B (k=1); b1.A(k=1) staged in iter0 ph1/2 ----
  stageA(sA0, 0, 0); stageA(sA0, 0, 1);
  stageB(sB0, 0, 0); stageB(sB0, 0, 1);
  stageB(sB1, 1, 0); stageB(sB1, 1, 1);
  asm volatile("s_waitcnt vmcnt(4)" ::: "memory");   // b0's 8 loads done, b1.B in flight
  __builtin_amdgcn_sched_barrier(0);
  BAR_SB();

#pragma unroll 1
  for (int it = 0; it < 6; ++it) {
    const int kA1 = 2 * it + 1;        // b1.A target (always valid)
    const int kB0 = 2 * it + 2;        // b0 target
    const int kB1 = 2 * it + 3;        // b1.B target
    const bool more = (it < 5);

    // ---- PH1 (buf0, quad0): read all B-frags + A q0; stage b1.A h0 ----
    DSREAD_B(sB0);
    DSREAD_A(sA0, 0);
    stageA(sA1, kA1, 0);
    __builtin_amdgcn_s_barrier();
    LGKM0();
    __builtin_amdgcn_s_setprio(1); MFMA_Q(0); __builtin_amdgcn_s_setprio(0);
    BAR_SB();

    // ---- PH2 ----
    DSREAD_A(sA0, 1);
    stageA(sA1, kA1, 1);
    __builtin_amdgcn_s_barrier();
    LGKM0();
    __builtin_amdgcn_s_setprio(1); MFMA_Q(1); __builtin_amdgcn_s_setprio(0);
    BAR_SB();

    // ---- PH3 ----
    DSREAD_A(sA0, 2);
    if (more) stageB(sB0, kB0, 0);
    __builtin_amdgcn_s_barrier();
    LGKM0();
    __builtin_amdgcn_s_setprio(1); MFMA_Q(2); __builtin_amdgcn_s_setprio(0);
    BAR_SB();

    // ---- PH4: counted wait (b1.B[prev] + b1.A h0/h1 must be resident for PH5) ----
    DSREAD_A(sA0, 3);
    if (more) stageB(sB0, kB0, 1);
    __builtin_amdgcn_s_barrier();
    LGKM0();
    __builtin_amdgcn_s_setprio(1); MFMA_Q(3); __builtin_amdgcn_s_setprio(0);
    if (more) { asm volatile("s_waitcnt vmcnt(4)" ::: "memory"); }
    else      { asm volatile("s_waitcnt vmcnt(0)" ::: "memory"); }
    __builtin_amdgcn_sched_barrier(0);
    BAR_SB();

    // ---- PH5 (buf1, quad0): read all B-frags + A q0; stage b0.A h0 ----
    DSREAD_B(sB1);
    DSREAD_A(sA1, 0);
    if (more) stageA(sA0, kB0, 0);
    __builtin_amdgcn_s_barrier();
    LGKM0();
    __builtin_amdgcn_s_setprio(1); MFMA_Q(0); __builtin_amdgcn_s_setprio(0);
    BAR_SB();

    // ---- PH6 ----
    DSREAD_A(sA1, 1);
    if (more) stageA(sA0, kB0, 1);
    __builtin_amdgcn_s_barrier();
    LGKM0();
    __builtin_amdgcn_s_setprio(1); MFMA_Q(1); __builtin_amdgcn_s_setprio(0);
    BAR_SB();

    // ---- PH7 ----
    DSREAD_A(sA1, 2);
    if (more) stageB(sB1, kB1, 0);
    __builtin_amdgcn_s_barrier();
    LGKM0();
    __builtin_amdgcn_s_setprio(1); MFMA_Q(2); __builtin_amdgcn_s_setprio(0);
    BAR_SB();

    // ---- PH8: counted wait (b0.B + b0.A must be resident for next PH1) ----
    DSREAD_A(sA1, 3);
    if (more) stageB(sB1, kB1, 1);
    __builtin_amdgcn_s_barrier();
    LGKM0();
    __builtin_amdgcn_s_setprio(1); MFMA_Q(3); __builtin_amdgcn_s_setprio(0);
    if (more) { asm volatile("s_waitcnt vmcnt(4)" ::: "memory");
                __builtin_amdgcn_sched_barrier(0); }
    BAR_SB();
  }

  // ---- epilogue: round-1 scattered stores. C/D layout col = lane&15, row = quad*4+reg ----
#pragma unroll
  for (int nf = 0; nf < 4; ++nf) {
    const int c = n0 + wc * 64 + nf * 16 + lrow;
    if (c < N_VOCAB) {
      const float bv = bias[c];
#pragma unroll
      for (int mf = 0; mf < 8; ++mf) {
        const long r0 = m0 + wr * 128 + mf * 16 + quad * 4;
#pragma unroll
        for (int rr = 0; rr < 4; ++rr)
          out[(r0 + rr) * (long)N_VOCAB + c] = acc[mf][nf][rr] + bv;
      }
    }
  }
}

#undef DSREAD_B
#undef DSREAD_A
#undef MFMA_Q
#undef BAR_SB
#undef LGKM0

// ---------------- IOU combine: one wave per (b,s,t) ----------------
__global__ __launch_bounds__(256) void iou_combine(const float* __restrict__ Xcat,
                                                   const float* __restrict__ b1,
                                                   const float* __restrict__ w2,
                                                   const float* __restrict__ b2,
                                                   float* __restrict__ out) {
  int gw = (blockIdx.x * 256 + threadIdx.x) >> 6;
  int lane = threadIdx.x & 63;
  if (gw >= 32 * 32 * 33) return;
  int b = gw / 1056;
  int rem = gw % 1056;
  int s = rem / 33;
  int t = rem % 33;
  int cidx = (s + t) >> 1;
  const float* ps = Xcat + (long)(b * 33 + s) * N_IOU;
  const float* pc = Xcat + (long)(b * 33 + cidx) * N_IOU + 768;
  const float* pe = Xcat + (long)(b * 33 + t) * N_IOU + 1536;
  float a0 = 0.f, a1 = 0.f, a2 = 0.f;
#pragma unroll
  for (int j = 0; j < 3; ++j) {
    int h0 = j * 256 + lane * 4;
    float4 vs = *(const float4*)(ps + h0);
    float4 vc = *(const float4*)(pc + h0);
    float4 ve = *(const float4*)(pe + h0);
    float4 vb = *(const float4*)(b1 + h0);
    const float* fs = (const float*)&vs;
    const float* fc = (const float*)&vc;
    const float* fe = (const float*)&ve;
    const float* fb = (const float*)&vb;
#pragma unroll
    for (int c = 0; c < 4; ++c) {
      float v = fmaxf(fs[c] + fc[c] + fe[c] + fb[c], 0.f);
      int h = h0 + c;
      a0 += v * w2[h * 3 + 0];
      a1 += v * w2[h * 3 + 1];
      a2 += v * w2[h * 3 + 2];
    }
  }
#pragma unroll
  for (int off = 32; off > 0; off >>= 1) {
    a0 += __shfl_down(a0, off, 64);
    a1 += __shfl_down(a1, off, 64);
    a2 += __shfl_down(a2, off, 64);
  }
  if (lane == 0) {
    int base = OUT_IOU_OFF + b * 3168 + s * 33 + t;   // ((b*3+k)*32+s)*33+t
    out[base + 0 * 1056] = a0 + b2[0];
    out[base + 1 * 1056] = a1 + b2[1];
    out[base + 2 * 1056] = a2 + b2[2];
  }
}

extern "C" void kernel_launch(void* const* d_in, const int* in_sizes, int n_in,
                              void* d_out, int out_size, void* d_ws, size_t ws_size,
                              hipStream_t stream) {
  const float* hst  = (const float*)d_in[0];  // (32,48,768)
  const float* hso  = (const float*)d_in[1];  // (32,33,768)
  const float* w_t1 = (const float*)d_in[2];  // (768,768)
  const float* b_t1 = (const float*)d_in[3];  // (768,)
  const float* w_t2 = (const float*)d_in[4];  // (768,30522)
  const float* b_t2 = (const float*)d_in[5];  // (30522,)
  const float* w_i1 = (const float*)d_in[6];  // (2304,768)
  const float* b_i1 = (const float*)d_in[7];  // (768,)
  const float* w_i2 = (const float*)d_in[8];  // (768,3)
  const float* b_i2 = (const float*)d_in[9];  // (3,)
  float* out = (float*)d_out;

  // workspace layout (bytes) — unchanged, end 68,812,800
  char* ws = (char*)d_ws;
  u16*   w_t2T = (u16*)(ws + 0);           // 30592*768*2 = 46,989,312
  u16*   xt    = (u16*)(ws + 46989312);    //  1536*768*2 =  2,359,296
  u16*   w_t1T = (u16*)(ws + 49348608);    //   768*768*2 =  1,179,648
  u16*   htext = (u16*)(ws + 50528256);    //  1536*768*2 =  2,359,296
  u16*   hcb   = (u16*)(ws + 52887552);    //  1152*768*2 =  1,769,472
  u16*   w_i1T = (u16*)(ws + 54657024);    //  2304*768*2 =  3,538,944
  float* Xcat  = (float*)(ws + 58195968);  // 1152*2304*4 = 10,616,832

  // 1) conversions (+mask) and all weight transposes: two launches total
  prep_cvt<<<dim3(2021), dim3(256), 0, stream>>>(hst, hso, xt, hcb, out);
  transpose_all<<<dim3(6312), dim3(256), 0, stream>>>(w_t1, w_t1T, w_t2, w_t2T, w_i1, w_i1T);

  // 2) both small GEMMs in one launch (text MODE1 + iou MODE2)
  gemm_small<<<dim3(234), dim3(256), 0, stream>>>(xt, w_t1T, htext, b_t1, hcb, w_i1T, Xcat);

  // 3) big vocab GEMM, then iou combine
  gemm_big<<<dim3(720), dim3(512), 0, stream>>>(htext, w_t2T, out, b_t2);
  iou_combine<<<dim3(8448), dim3(256), 0, stream>>>(Xcat, b_i1, w_i2, b_i2, out);
}